// Round 14
// baseline (410.523 us; speedup 1.0000x reference)
//
#include <hip/hip_runtime.h>
#include <math.h>

#define T_SAMPLES 96000
#define NFRAMES 801
#define NBINS 513
#define FROWS 515   // NBINS + 2 guard rows (index f+1; rows 0 and 514 are zero)
#define MAGT 804    // mag row stride (floats): 16B-aligned rows for float4 stores
#define EPS32 1.1920928955078125e-07f

typedef _Float16 f16;
typedef f16 f16x2 __attribute__((ext_vector_type(2)));
typedef f16 f16x4 __attribute__((ext_vector_type(4)));
typedef f16 f16x8 __attribute__((ext_vector_type(8)));
typedef float f32x4 __attribute__((ext_vector_type(4)));
typedef float f32x16 __attribute__((ext_vector_type(16)));

// ---------------------------- fused prep + pad zeroing + STFT (v3) --------
// Blocks 0..160  : weight-norm + A-pack
// Blocks 161..416: zero guard rows / tail cols of the 5 fp16 copies
// Blocks 417..820: STFT — 8 frames/block as 4 packed pairs, each 1024-pt
//   complex Stockham FFT run by ALL 256 threads (33 KB LDS -> 4 blocks/CU).
//   Unpack X1=(Z(k)+conj(Z(N-k)))/2, X2=-i(Z(k)-conj(Z(N-k)))/2; mags staged
//   in LDS, stored as two aligned float4 per f row (stride MAGT).
__global__ __launch_bounds__(256) void prep_stft_kernel(
    const float* __restrict__ y, float* __restrict__ mag,
    const float* __restrict__ v0, const float* __restrict__ g0,
    const float* __restrict__ v1, const float* __restrict__ g1,
    const float* __restrict__ v2, const float* __restrict__ g2,
    const float* __restrict__ v3, const float* __restrict__ g3,
    const float* __restrict__ v4, const float* __restrict__ g4,
    const float* __restrict__ vo, const float* __restrict__ go,
    float* __restrict__ w0n, float* __restrict__ won,
    f16* __restrict__ A1, f16* __restrict__ A2,
    f16* __restrict__ A3, f16* __restrict__ A4,
    f16* __restrict__ f0c, f16* __restrict__ f1c, f16* __restrict__ f2c,
    f16* __restrict__ f3c, f16* __restrict__ f4c)
{
    __shared__ float2 fbuf[2][1024];        // 16 KB (prep reuses as scratch)
    __shared__ float mg[8][520];            // 16.6 KB
    const int MGS = 520;

    int blk = blockIdx.x;
    int tid = threadIdx.x;

    if (blk >= 417) {                       // ---------------- STFT part ----
        int s = blk - 417;
        int b = s / 101;
        int t0 = (s - b * 101) * 8;
        const float* yb = y + (size_t)b * T_SAMPLES;

        #pragma unroll 1
        for (int pp = 0; pp < 4; ++pp) {
            int tA = t0 + 2 * pp;
            #pragma unroll
            for (int it = 0; it < 4; ++it) {
                int n = tid + it * 256;
                float w = 0.f;
                int np_ = n - 212;
                if (np_ >= 0 && np_ < 600)
                    w = 0.5f * (1.0f - cospif((float)np_ * (1.0f / 300.0f)));
                int j1 = tA * 120 + n - 512;
                if (j1 < 0) j1 = -j1;
                if (j1 >= T_SAMPLES) j1 = 2 * T_SAMPLES - 2 - j1;
                int j2 = tA * 120 + 120 + n - 512;
                if (j2 < 0) j2 = -j2;
                if (j2 >= T_SAMPLES) j2 = 2 * T_SAMPLES - 2 - j2;
                fbuf[0][n] = make_float2(w * yb[j1], w * yb[j2]);
            }
            __syncthreads();

            int srcb = 0;
            #pragma unroll
            for (int stage = 0; stage < 10; ++stage) {
                int m = 1 << stage;
                #pragma unroll
                for (int it = 0; it < 2; ++it) {
                    int idx = tid + it * 256;            // 0..511
                    int jm  = (idx >> stage) << stage;
                    float jf = (float)jm * (1.0f / 512.0f);
                    float wr = cospif(jf);
                    float wi = -sinpif(jf);
                    float2 a  = fbuf[srcb][idx];
                    float2 bb = fbuf[srcb][idx + 512];
                    float2 sm = make_float2(a.x + bb.x, a.y + bb.y);
                    float2 d  = make_float2(a.x - bb.x, a.y - bb.y);
                    float2 dw = make_float2(d.x * wr - d.y * wi, d.x * wi + d.y * wr);
                    fbuf[srcb ^ 1][idx + jm]     = sm;
                    fbuf[srcb ^ 1][idx + jm + m] = dw;
                }
                __syncthreads();
                srcb ^= 1;
            }
            // srcb == 0: results in fbuf[0]

            for (int k = tid; k < 513; k += 256) {
                float2 zk = fbuf[0][k];
                float2 zr = fbuf[0][(1024 - k) & 1023];
                float x1r = 0.5f * (zk.x + zr.x);
                float x1i = 0.5f * (zk.y - zr.y);
                float x2r = 0.5f * (zk.y + zr.y);
                float x2i = 0.5f * (zr.x - zk.x);
                mg[2 * pp][k]     = sqrtf(fmaxf(x1r * x1r + x1i * x1i, EPS32));
                mg[2 * pp + 1][k] = sqrtf(fmaxf(x2r * x2r + x2i * x2i, EPS32));
            }
            __syncthreads();   // fbuf reused by next pair
        }

        for (int f = tid; f < 513; f += 256) {
            size_t base = ((size_t)(b * NBINS) + f) * MAGT + t0;
            if (t0 + 7 < NFRAMES) {
                f32x4 q0 = {mg[0][f], mg[1][f], mg[2][f], mg[3][f]};
                f32x4 q1 = {mg[4][f], mg[5][f], mg[6][f], mg[7][f]};
                *reinterpret_cast<f32x4*>(&mag[base])     = q0;
                *reinterpret_cast<f32x4*>(&mag[base + 4]) = q1;
            } else {
                #pragma unroll
                for (int p = 0; p < 8; ++p)
                    if (t0 + p < NFRAMES) mag[base + p] = mg[p][f];
            }
        }
        return;
    }

    if (blk >= 161) {                       // ---- pad zeroing part
        int zb = blk - 161;                 // 0..255
        const int TPs[5]   = {840, 456, 264, 136, 136};
        const int tails[5] = {840, 420, 228, 133, 136};
        f16* ptrs[5] = {f0c, f1c, f2c, f3c, f4c};
        f16x8 z;
        #pragma unroll
        for (int j = 0; j < 8; ++j) z[j] = (f16)0.f;
        for (int l = 0; l < 5; ++l) {
            f16* p = ptrs[l];
            int TP = TPs[l], tail = tails[l];
            int rowSlots   = TP * 4;
            int guardSlots = 8 * rowSlots;
            int tailCols   = TP - tail;
            int tailSlots  = 4 * FROWS * tailCols * 4;
            int total = guardSlots + tailSlots;
            for (int i = zb * 256 + tid; i < total; i += 256 * 256) {
                size_t slot;
                if (i < guardSlots) {
                    int rs = i / rowSlots;
                    int q  = i - rs * rowSlots;
                    int b  = rs >> 1;
                    int r  = (rs & 1) ? (FROWS - 1) : 0;
                    slot = ((size_t)(b * FROWS + r)) * rowSlots + q;
                } else {
                    int j2 = i - guardSlots;
                    int per = tailCols * 4;
                    int row = j2 / per;
                    int q   = j2 - row * per;
                    slot = ((size_t)row * TP + tail) * 4 + q;
                }
                *reinterpret_cast<f16x8*>((char*)p + slot * 16) = z;
            }
        }
        return;
    }

    // ---- weight-norm / A-pack part
    const float *v, *g; f16* Ap = nullptr; float* outf = nullptr;
    int o, per_o, KW = 9;
    if (blk < 32)        { v = v1; g = g1; Ap = A1; o = blk;       per_o = 864; }
    else if (blk < 64)   { v = v2; g = g2; Ap = A2; o = blk - 32;  per_o = 864; }
    else if (blk < 96)   { v = v3; g = g3; Ap = A3; o = blk - 64;  per_o = 864; }
    else if (blk < 128)  { v = v4; g = g4; Ap = A4; o = blk - 96;  per_o = 288; KW = 3; }
    else if (blk < 160)  { v = v0; g = g0; outf = w0n; o = blk - 128; per_o = 49; }
    else                 { v = vo; g = go; outf = won; o = 0;        per_o = 288; }

    float* red = (float*)&fbuf[0][0];
    const float* vv = v + (size_t)o * per_o;
    float s = 0.f;
    for (int i = tid; i < per_o; i += 256) { float x = vv[i]; s = fmaf(x, x, s); }
    red[tid] = s;
    __syncthreads();
    for (int k = 128; k > 0; k >>= 1) {
        if (tid < k) red[tid] += red[tid + k];
        __syncthreads();
    }
    float scale = g[o] / sqrtf(red[0]);

    if (outf) {
        for (int i = tid; i < per_o; i += 256)
            outf[(size_t)o * per_o + i] = vv[i] * scale;
    } else {
        for (int i = tid; i < per_o; i += 256) {
            int tap = i >> 5;
            int c   = i & 31;
            int df  = tap / KW, kw = tap - df * KW;
            float val = vv[(c * 3 + df) * KW + kw] * scale;
            int l = ((c >> 3) & 1) * 32 + o;
            int ch = c >> 4;
            int j = c & 7;
            Ap[(((tap * 2 + ch) * 64 + l) << 3) + j] = (f16)val;
        }
    }
}

// -------------------------------------------------------- harmonic conv ----
__global__ __launch_bounds__(256) void harmonic_kernel(const float* __restrict__ mag,
                                                       const float* __restrict__ wn,
                                                       const float* __restrict__ bias,
                                                       float* __restrict__ out,
                                                       f16* __restrict__ f0c,
                                                       float fr4, float fr5)
{
    int f = blockIdx.x;
    int b = blockIdx.y;
    int tid = threadIdx.x;

    __shared__ float rows[3][808];

    const float* mb = mag + (size_t)b * NBINS * MAGT;

    for (int i = tid; i < 808; i += 256) {
        int tt = i - 3;
        bool ok = (tt >= 0) && (tt < NFRAMES);
        float m336 = (ok && f >= 336) ? mb[(size_t)(f - 336) * MAGT + tt] : 0.f;
        float m337 = (ok && f >= 337) ? mb[(size_t)(f - 337) * MAGT + tt] : 0.f;
        float m154 = (ok && f >= 154) ? mb[(size_t)(f - 154) * MAGT + tt] : 0.f;
        float m155 = (ok && f >= 155) ? mb[(size_t)(f - 155) * MAGT + tt] : 0.f;
        float m0   = ok ? mb[(size_t)f * MAGT + tt] : 0.f;
        rows[0][i] = (1.f - fr4) * m336 + fr4 * m337;
        rows[1][i] = (1.f - fr5) * m154 + fr5 * m155;
        rows[2][i] = m0;
    }
    __syncthreads();

    char* crow = (char*)f0c + ((size_t)(b * FROWS + f + 1)) * 840 * 64;

    // left pad zeros: tg in [0,4)
    if (tid < 16) {
        int tg = tid >> 2, q = tid & 3;
        int swz = (((tg >> 1) & 3) << 4) | (((tg >> 3) & 1) << 6);
        f16x8 z;
        #pragma unroll
        for (int j = 0; j < 8; ++j) z[j] = (f16)0.f;
        *reinterpret_cast<f16x8*>(crow + ((tg * 64 + q * 16) ^ swz)) = z;
    }

    #pragma unroll
    for (int chunk = 0; chunk < 4; ++chunk) {
        int t = chunk * 256 + tid;
        if (t < NFRAMES) {
            float win[3][7];
            #pragma unroll
            for (int r = 0; r < 3; ++r)
                #pragma unroll
                for (int k = 0; k < 7; ++k)
                    win[r][k] = rows[r][t + k];

            float vals[32];
            #pragma unroll
            for (int o = 0; o < 32; ++o) {
                float a = bias[o];
                #pragma unroll
                for (int r = 0; r < 3; ++r) {
                    const float* wr = wn + (o * 7 + 4 + r) * 7;
                    #pragma unroll
                    for (int kw = 0; kw < 7; ++kw)
                        a = fmaf(win[r][kw], wr[kw], a);
                }
                vals[o] = (a > 0.f) ? a : 0.1f * a;
            }

            #pragma unroll
            for (int o = 0; o < 32; ++o)
                __builtin_nontemporal_store(vals[o],
                    &out[(((size_t)b * 32 + o) * NBINS + f) * (size_t)NFRAMES + t]);

            int tg = t + 4;
            int swz = (((tg >> 1) & 3) << 4) | (((tg >> 3) & 1) << 6);
            #pragma unroll
            for (int q = 0; q < 4; ++q) {
                f16x8 h;
                #pragma unroll
                for (int j = 0; j < 8; ++j) h[j] = (f16)vals[q * 8 + j];
                *reinterpret_cast<f16x8*>(crow + ((tg * 64 + q * 16) ^ swz)) = h;
            }
        } else if (t < 836) {                 // right pad zeros: tg in [805,840)
            int tg = t + 4;
            int swz = (((tg >> 1) & 3) << 4) | (((tg >> 3) & 1) << 6);
            f16x8 z;
            #pragma unroll
            for (int j = 0; j < 8; ++j) z[j] = (f16)0.f;
            #pragma unroll
            for (int q = 0; q < 4; ++q)
                *reinterpret_cast<f16x8*>(crow + ((tg * 64 + q * 16) ^ swz)) = z;
        }
    }
}

// ------------------------------------------------ one-shot MFMA conv v6 ----
template<int KW, int STRIDE, int PW, int PAD_IN, int PAD_OUT, int NTB, int MINW, bool DO_LRELU>
__global__ __launch_bounds__(256, MINW) void conv_v6(
    const f16* __restrict__ inC, const f16* __restrict__ Ap,
    const float* __restrict__ bias, float* __restrict__ out,
    f16* __restrict__ outC, int Tout, int TpadIn, int TpadOut)
{
    constexpr int NT    = 64;
    constexpr int TR    = NT * STRIDE + KW - 1;
    constexpr int TRP   = (TR + 1) & ~1;
    constexpr int ROWB  = TRP * 64;
    constexpr int SLR   = TRP * 4;             // 16B slots per f-row
    constexpr int SL    = 6 * SLR;             // active slots
    constexpr int KPT   = (SL + 255) / 256;    // issue groups (unconditional)
    constexpr int TOFF  = (PAD_IN - PW) & 15;
    constexpr int NFOFF = 32 * STRIDE * 64;

    __shared__ char ldsb[KPT * 256 * 16];      // padded: slack absorbs tail group

    const int tid  = threadIdx.x;
    const int lane = tid & 63;
    const int wave = tid >> 6;

    // bijective XCD swizzle (m204), work order: tb fastest, then fblk, then b
    const int NWG = NTB * 129 * 4;
    int lin = blockIdx.x;
    int xcd = lin & 7, sl = lin >> 3;
    const int q = NWG / 8, r = NWG % 8;
    int work = (xcd < r ? xcd * (q + 1) : r * (q + 1) + (xcd - r) * q) + sl;
    const int tb   = work % NTB;
    int rem        = work / NTB;
    const int fblk = rem % 129;
    const int b    = rem / 129;
    const int f0   = fblk * 4;
    const int brow = b * FROWS + f0;           // copy row of fr=0 (fi=f0-1)
    const int t0   = tb * NT;
    const int base_t = t0 * STRIDE + (PAD_IN - PW);

    // ---- stage: branch-free global_load_lds, linear LDS dest
    {
        const char* inB = (const char*)inC;
        #pragma unroll
        for (int k = 0; k < KPT; ++k) {
            int s  = tid + k * 256;
            int fr = s / SLR;
            int s2 = s - fr * SLR;
            __builtin_amdgcn_global_load_lds(
                (const __attribute__((address_space(1))) void*)
                    (inB + ((size_t)(brow + fr) * TpadIn + base_t) * 64 + (size_t)s2 * 16),
                (__attribute__((address_space(3))) void*)
                    (ldsb + (k * 256 + (tid & 192)) * 16),
                16, 0, 0);
        }
    }

    // swizzled LDS read bases
    const int tln = lane & 31;
    const int hi  = lane >> 5;
    int baddr0[KW];
    #pragma unroll
    for (int kw = 0; kw < KW; ++kw) {
        int trow = tln * STRIDE + kw;
        int x = trow + TOFF;
        int swz = (((x >> 1) & 3) << 4) | (((x >> 3) & 1) << 6);
        baddr0[kw] = (trow * 64 + hi * 16) ^ swz;
    }

    float bs[16];
    #pragma unroll
    for (int rr = 0; rr < 16; ++rr) bs[rr] = bias[4 * hi + 8 * (rr >> 2) + (rr & 3)];

    __syncthreads();   // drains vmcnt(0): staged tile ready

    f32x16 acc[2];
    #pragma unroll
    for (int nf = 0; nf < 2; ++nf)
        #pragma unroll
        for (int rr = 0; rr < 16; ++rr) acc[nf][rr] = 0.f;

    const char* lrow = ldsb + wave * ROWB;
    #pragma unroll
    for (int df = 0; df < 3; ++df) {
        f16x8 a[KW * 2];
        #pragma unroll
        for (int kw = 0; kw < KW; ++kw)
            #pragma unroll
            for (int ch = 0; ch < 2; ++ch)
                a[kw * 2 + ch] = *reinterpret_cast<const f16x8*>(
                    Ap + (((df * KW + kw) * 2 + ch) << 9) + lane * 8);
        #pragma unroll
        for (int kw = 0; kw < KW; ++kw)
            #pragma unroll
            for (int ch = 0; ch < 2; ++ch)
                #pragma unroll
                for (int nf = 0; nf < 2; ++nf) {
                    f16x8 bf = *reinterpret_cast<const f16x8*>(
                        lrow + ((baddr0[kw] ^ (ch << 5)) + df * ROWB + nf * NFOFF));
                    acc[nf] = __builtin_amdgcn_mfma_f32_32x32x16_f16(a[kw * 2 + ch], bf, acc[nf], 0, 0, 0);
                }
    }

    // ---------------- epilogue ----------------
    const int f = f0 + wave;
    if (f >= NBINS) return;

    char* crow = nullptr;
    if constexpr (PAD_OUT > 0)
        crow = (char*)outC + ((size_t)(b * FROWS + f + 1)) * TpadOut * 64;

    #pragma unroll
    for (int nf = 0; nf < 2; ++nf) {
        int t = t0 + nf * 32 + tln;
        bool vt = (t < Tout);
        float vals[16];
        #pragma unroll
        for (int rr = 0; rr < 16; ++rr) {
            float v = acc[nf][rr] + bs[rr];
            if (DO_LRELU) v = (v > 0.f) ? v : 0.1f * v;
            vals[rr] = v;
        }
        if (vt) {
            #pragma unroll
            for (int rr = 0; rr < 16; ++rr) {
                int o = 4 * hi + 8 * (rr >> 2) + (rr & 3);
                __builtin_nontemporal_store(vals[rr],
                    &out[(((size_t)b * 32 + o) * NBINS + f) * Tout + t]);
            }
        }
        if constexpr (PAD_OUT > 0) {
            int tg = t + PAD_OUT;
            int swz = (((tg >> 1) & 3) << 4) | (((tg >> 3) & 1) << 6);
            int rowbyte = (tg * 64) ^ swz;
            #pragma unroll
            for (int qq = 0; qq < 4; ++qq) {
                f16x4 hv;
                #pragma unroll
                for (int rr = 0; rr < 4; ++rr)
                    hv[rr] = vt ? (f16)vals[4 * qq + rr] : (f16)0.f;
                *reinterpret_cast<f16x4*>(crow + (rowbyte ^ ((4 * hi + 8 * qq) << 1))) = hv;
            }
        }
    }
    if constexpr (PAD_OUT > 0) {
        if (tb == 0 && lane < PAD_OUT * 4) {   // left pad zeros
            int tgp = lane >> 2, oct = lane & 3;
            f16x8 z;
            #pragma unroll
            for (int j = 0; j < 8; ++j) z[j] = (f16)0.f;
            *reinterpret_cast<f16x8*>(crow + tgp * 64 + oct * 16) = z;
        }
    }
}

// ------------------------------------------------------- final conv v2 ----
__global__ __launch_bounds__(256) void convo_v2(const f16* __restrict__ inC,
                                                const float* __restrict__ won,
                                                const float* __restrict__ bias,
                                                float* __restrict__ f5,
                                                float* __restrict__ flat)
{
    const int TP4 = 136;
    int blk = blockIdx.x;                  // (b, fpair)
    int b = blk / 257, fp = blk - (b * 257);
    int tid = threadIdx.x;
    int f = fp * 2 + (tid >> 7);
    int t = tid & 127;
    if (f >= NBINS || t >= 101) return;

    float acc = bias[0];
    #pragma unroll
    for (int df = 0; df < 3; ++df) {
        const char* row = (const char*)inC + ((size_t)(b * FROWS + f + df)) * TP4 * 64;
        #pragma unroll
        for (int kw = 0; kw < 3; ++kw) {
            int tg = t + kw;               // (t + kw - 1) + PAD_OUT(1)
            int swz = (((tg >> 1) & 3) << 4) | (((tg >> 3) & 1) << 6);
            #pragma unroll
            for (int q2 = 0; q2 < 4; ++q2) {
                f16x8 h = *reinterpret_cast<const f16x8*>(row + ((tg * 64 + q2 * 16) ^ swz));
                #pragma unroll
                for (int j = 0; j < 8; ++j)
                    acc = fmaf((float)h[j], won[((q2 * 8 + j) * 3 + df) * 3 + kw], acc);
            }
        }
    }
    size_t idx = ((size_t)(b * NBINS + f)) * 101 + t;
    __builtin_nontemporal_store(acc, &f5[idx]);
    __builtin_nontemporal_store(acc, &flat[idx]);
}

// ------------------------------------------------------------------ launch --
extern "C" void kernel_launch(void* const* d_in, const int* in_sizes, int n_in,
                              void* d_out, int out_size, void* d_ws, size_t ws_size,
                              hipStream_t stream)
{
    const float* y  = (const float*)d_in[0];
    const float* v0 = (const float*)d_in[1];
    const float* g0 = (const float*)d_in[2];
    const float* b0 = (const float*)d_in[3];
    const float* v1 = (const float*)d_in[4];
    const float* g1 = (const float*)d_in[5];
    const float* b1 = (const float*)d_in[6];
    const float* v2 = (const float*)d_in[7];
    const float* g2 = (const float*)d_in[8];
    const float* b2 = (const float*)d_in[9];
    const float* v3 = (const float*)d_in[10];
    const float* g3 = (const float*)d_in[11];
    const float* b3 = (const float*)d_in[12];
    const float* v4 = (const float*)d_in[13];
    const float* g4 = (const float*)d_in[14];
    const float* b4 = (const float*)d_in[15];
    const float* vo = (const float*)d_in[16];
    const float* go = (const float*)d_in[17];
    const float* bo = (const float*)d_in[18];

    float* out = (float*)d_out;
    float* ws  = (float*)d_ws;

    const size_t SFLAT = (size_t)4 * NBINS * 101;
    const size_t NF0   = (size_t)4 * 32 * NBINS * 801;
    const size_t NF1   = (size_t)4 * 32 * NBINS * 401;
    const size_t NF2   = (size_t)4 * 32 * NBINS * 201;
    const size_t NF3   = (size_t)4 * 32 * NBINS * 101;
    float* oflat = out;
    float* f0 = out + SFLAT;
    float* f1 = f0 + NF0;
    float* f2 = f1 + NF1;
    float* f3 = f2 + NF2;
    float* f4 = f3 + NF3;
    float* f5 = f4 + NF3;

    // mag (stride MAGT) stashed in the (not yet written) fmap1 region
    float* mag = f1;

    // ws layout: fp32 small weights, fp16 A-packs, fp16 activation copies
    const int TP0 = 840, TP1 = 456, TP2 = 264, TP3 = 136, TP4 = 136;
    size_t off = 0;
    float* w0n = ws + off; off += 1568;
    float* won = ws + off; off += 288;
    f16* A1 = (f16*)(ws + off);
    f16* A2 = A1 + 27648;
    f16* A3 = A2 + 27648;
    f16* A4 = A3 + 27648;               // 9216 elements
    f16* f0c = A4 + 9216;               // [4][515][840][32]
    f16* f1c = f0c + (size_t)4 * FROWS * TP0 * 32;   // [4][515][456][32]
    f16* f2c = f1c + (size_t)4 * FROWS * TP1 * 32;   // [4][515][264][32]
    f16* f3c = f2c + (size_t)4 * FROWS * TP2 * 32;   // [4][515][136][32]
    f16* f4c = f3c + (size_t)4 * FROWS * TP3 * 32;   // [4][515][136][32]

    prep_stft_kernel<<<821, 256, 0, stream>>>(y, mag,
                                              v0, g0, v1, g1, v2, g2, v3, g3,
                                              v4, g4, vo, go, w0n, won,
                                              A1, A2, A3, A4,
                                              f0c, f1c, f2c, f3c, f4c);

    double sh4 = -(1000.0 * log(0.001 * (5.0 / 7.0)) - 1000.0 * log(0.001)); // 336.472...
    double sh5 = -(1000.0 * log(0.001 * (6.0 / 7.0)) - 1000.0 * log(0.001)); // 154.150...
    float fr4 = (float)(sh4 - floor(sh4));
    float fr5 = (float)(sh5 - floor(sh5));

    harmonic_kernel<<<dim3(NBINS, 4), 256, 0, stream>>>(mag, w0n, b0, f0, f0c, fr4, fr5);

    // conv chain: one-shot gload_lds-staged, fp16-copy in, fp32 fmap out (+ copy)
    conv_v6<9, 2, 4, 4, 4, 7, 3, true><<<7 * 129 * 4, 256, 0, stream>>>(f0c, A1, b1, f1, f1c, 401, TP0, TP1);
    conv_v6<9, 2, 4, 4, 4, 4, 3, true><<<4 * 129 * 4, 256, 0, stream>>>(f1c, A2, b2, f2, f2c, 201, TP1, TP2);
    conv_v6<9, 2, 4, 4, 5, 2, 3, true><<<2 * 129 * 4, 256, 0, stream>>>(f2c, A3, b3, f3, f3c, 101, TP2, TP3);
    conv_v6<3, 1, 1, 5, 1, 2, 4, true><<<2 * 129 * 4, 256, 0, stream>>>(f3c, A4, b4, f4, f4c, 101, TP3, TP4);

    convo_v2<<<257 * 4, 256, 0, stream>>>(f4c, won, bo, f5, oflat);
}

// Round 15
// 393.907 us; speedup vs baseline: 1.0422x; 1.0422x over previous
//
#include <hip/hip_runtime.h>
#include <math.h>

#define T_SAMPLES 96000
#define NFRAMES 801
#define NBINS 513
#define FROWS 515   // NBINS + 2 guard rows (index f+1; rows 0 and 514 are zero)
#define MAGT 804    // mag row stride (floats): 16B-aligned rows for float4 stores
#define EPS32 1.1920928955078125e-07f

typedef _Float16 f16;
typedef f16 f16x2 __attribute__((ext_vector_type(2)));
typedef f16 f16x4 __attribute__((ext_vector_type(4)));
typedef f16 f16x8 __attribute__((ext_vector_type(8)));
typedef float f32x4 __attribute__((ext_vector_type(4)));
typedef float f32x16 __attribute__((ext_vector_type(16)));

// -------------------------------------------------------------- STFT v2 ----
// 256 threads = 4 waves; each wave FFTs a PAIR of frames packed as complex
// z = x1 + i*x2 (one 1024-pt Stockham per 2 frames). Unpack:
//   X1(k) = (Z(k)+conj(Z(N-k)))/2,  X2(k) = -i(Z(k)-conj(Z(N-k)))/2.
// Mags staged in LDS (overlay of the free ping half), then written as two
// aligned float4 per (f, 8-frame block) -> sector-aligned coalesced stores.
__global__ __launch_bounds__(256) void stft_v2(const float* __restrict__ y,
                                               float* __restrict__ mag)
{
    __shared__ float2 fft[2][4][1024];           // 64 KB; results end in fft[0]
    float* mg = (float*)&fft[1][0][0];           // [8][520] overlay (16.6 KB)
    const int MGS = 520;

    const int tid  = threadIdx.x;
    const int lane = tid & 63;
    const int wv   = tid >> 6;
    const int t0   = blockIdx.x * 8;
    const int b    = blockIdx.y;
    const float* yb = y + (size_t)b * T_SAMPLES;

    // ---- load + window two frames, packed
    const int tA = t0 + 2 * wv;
    for (int n = lane; n < 1024; n += 64) {
        float w = 0.f;
        int np_ = n - 212;
        if (np_ >= 0 && np_ < 600)
            w = 0.5f * (1.0f - cospif((float)np_ * (1.0f / 300.0f)));
        int j1 = tA * 120 + n - 512;
        if (j1 < 0) j1 = -j1;
        if (j1 >= T_SAMPLES) j1 = 2 * T_SAMPLES - 2 - j1;
        int j2 = tA * 120 + 120 + n - 512;
        if (j2 < 0) j2 = -j2;
        if (j2 >= T_SAMPLES) j2 = 2 * T_SAMPLES - 2 - j2;
        fft[0][wv][n] = make_float2(w * yb[j1], w * yb[j2]);
    }
    __syncthreads();

    // ---- 10-stage Stockham (per-wave, ping-pong)
    int srcb = 0;
    #pragma unroll
    for (int stage = 0; stage < 10; ++stage) {
        int m = 1 << stage;
        #pragma unroll
        for (int it = 0; it < 8; ++it) {
            int idx = lane + it * 64;             // 0..511
            int jm  = (idx >> stage) << stage;
            float jf = (float)jm * (1.0f / 512.0f);
            float wr = cospif(jf);
            float wi = -sinpif(jf);
            float2 a  = fft[srcb][wv][idx];
            float2 bb = fft[srcb][wv][idx + 512];
            float2 s  = make_float2(a.x + bb.x, a.y + bb.y);
            float2 d  = make_float2(a.x - bb.x, a.y - bb.y);
            float2 dw = make_float2(d.x * wr - d.y * wi, d.x * wi + d.y * wr);
            fft[srcb ^ 1][wv][idx + jm]     = s;
            fft[srcb ^ 1][wv][idx + jm + m] = dw;
        }
        __syncthreads();
        srcb ^= 1;
    }
    // srcb == 0: results in fft[0]; fft[1] free -> mg overlay

    // ---- unpack + magnitudes into mg[frame][k]
    for (int k = lane; k < 513; k += 64) {
        float2 zk = fft[0][wv][k];
        float2 zr = fft[0][wv][(1024 - k) & 1023];
        float x1r = 0.5f * (zk.x + zr.x);
        float x1i = 0.5f * (zk.y - zr.y);
        float x2r = 0.5f * (zk.y + zr.y);
        float x2i = 0.5f * (zr.x - zk.x);
        mg[(2 * wv)     * MGS + k] = sqrtf(fmaxf(x1r * x1r + x1i * x1i, EPS32));
        mg[(2 * wv + 1) * MGS + k] = sqrtf(fmaxf(x2r * x2r + x2i * x2i, EPS32));
    }
    __syncthreads();

    // ---- transposed coalesced store: mag[b][f][t0..t0+7]
    for (int f = tid; f < 513; f += 256) {
        size_t base = ((size_t)(b * NBINS) + f) * MAGT + t0;
        if (t0 + 7 < NFRAMES) {
            f32x4 v0 = {mg[0 * MGS + f], mg[1 * MGS + f], mg[2 * MGS + f], mg[3 * MGS + f]};
            f32x4 v1 = {mg[4 * MGS + f], mg[5 * MGS + f], mg[6 * MGS + f], mg[7 * MGS + f]};
            *reinterpret_cast<f32x4*>(&mag[base])     = v0;
            *reinterpret_cast<f32x4*>(&mag[base + 4]) = v1;
        } else {
            #pragma unroll
            for (int p = 0; p < 8; ++p)
                if (t0 + p < NFRAMES) mag[base + p] = mg[p * MGS + f];
        }
    }
}

// -------------------------------------- fused weight prep + pad zeroing ----
__global__ __launch_bounds__(256) void prep_kernel(
    const float* __restrict__ v0, const float* __restrict__ g0,
    const float* __restrict__ v1, const float* __restrict__ g1,
    const float* __restrict__ v2, const float* __restrict__ g2,
    const float* __restrict__ v3, const float* __restrict__ g3,
    const float* __restrict__ v4, const float* __restrict__ g4,
    const float* __restrict__ vo, const float* __restrict__ go,
    float* __restrict__ w0n, float* __restrict__ won,
    f16* __restrict__ A1, f16* __restrict__ A2,
    f16* __restrict__ A3, f16* __restrict__ A4,
    f16* __restrict__ f0c, f16* __restrict__ f1c, f16* __restrict__ f2c,
    f16* __restrict__ f3c, f16* __restrict__ f4c)
{
    int blk = blockIdx.x;
    int tid = threadIdx.x;

    if (blk >= 161) {                       // ---- pad zeroing part
        int zb = blk - 161;                 // 0..255
        const int TPs[5]   = {840, 456, 264, 136, 136};
        const int tails[5] = {840, 420, 228, 133, 136};
        f16* ptrs[5] = {f0c, f1c, f2c, f3c, f4c};
        f16x8 z;
        #pragma unroll
        for (int j = 0; j < 8; ++j) z[j] = (f16)0.f;
        for (int l = 0; l < 5; ++l) {
            f16* p = ptrs[l];
            int TP = TPs[l], tail = tails[l];
            int rowSlots   = TP * 4;
            int guardSlots = 8 * rowSlots;
            int tailCols   = TP - tail;
            int tailSlots  = 4 * FROWS * tailCols * 4;
            int total = guardSlots + tailSlots;
            for (int i = zb * 256 + tid; i < total; i += 256 * 256) {
                size_t slot;
                if (i < guardSlots) {
                    int rs = i / rowSlots;
                    int q  = i - rs * rowSlots;
                    int b  = rs >> 1;
                    int r  = (rs & 1) ? (FROWS - 1) : 0;
                    slot = ((size_t)(b * FROWS + r)) * rowSlots + q;
                } else {
                    int j2 = i - guardSlots;
                    int per = tailCols * 4;
                    int row = j2 / per;
                    int q   = j2 - row * per;
                    slot = ((size_t)row * TP + tail) * 4 + q;
                }
                *reinterpret_cast<f16x8*>((char*)p + slot * 16) = z;
            }
        }
        return;
    }

    const float *v, *g; f16* Ap = nullptr; float* outf = nullptr;
    int o, per_o, KW = 9;
    if (blk < 32)        { v = v1; g = g1; Ap = A1; o = blk;       per_o = 864; }
    else if (blk < 64)   { v = v2; g = g2; Ap = A2; o = blk - 32;  per_o = 864; }
    else if (blk < 96)   { v = v3; g = g3; Ap = A3; o = blk - 64;  per_o = 864; }
    else if (blk < 128)  { v = v4; g = g4; Ap = A4; o = blk - 96;  per_o = 288; KW = 3; }
    else if (blk < 160)  { v = v0; g = g0; outf = w0n; o = blk - 128; per_o = 49; }
    else                 { v = vo; g = go; outf = won; o = 0;        per_o = 288; }

    const float* vv = v + (size_t)o * per_o;
    __shared__ float red[256];
    float s = 0.f;
    for (int i = tid; i < per_o; i += 256) { float x = vv[i]; s = fmaf(x, x, s); }
    red[tid] = s;
    __syncthreads();
    for (int k = 128; k > 0; k >>= 1) {
        if (tid < k) red[tid] += red[tid + k];
        __syncthreads();
    }
    float scale = g[o] / sqrtf(red[0]);

    if (outf) {
        for (int i = tid; i < per_o; i += 256)
            outf[(size_t)o * per_o + i] = vv[i] * scale;
    } else {
        for (int i = tid; i < per_o; i += 256) {
            int tap = i >> 5;
            int c   = i & 31;
            int df  = tap / KW, kw = tap - df * KW;
            float val = vv[(c * 3 + df) * KW + kw] * scale;
            int l = ((c >> 3) & 1) * 32 + o;
            int ch = c >> 4;
            int j = c & 7;
            Ap[(((tap * 2 + ch) * 64 + l) << 3) + j] = (f16)val;
        }
    }
}

// -------------------------------------------------------- harmonic conv ----
__global__ __launch_bounds__(256) void harmonic_kernel(const float* __restrict__ mag,
                                                       const float* __restrict__ wn,
                                                       const float* __restrict__ bias,
                                                       float* __restrict__ out,
                                                       f16* __restrict__ f0c,
                                                       float fr4, float fr5)
{
    int f = blockIdx.x;
    int b = blockIdx.y;
    int tid = threadIdx.x;

    __shared__ float rows[3][808];

    const float* mb = mag + (size_t)b * NBINS * MAGT;

    for (int i = tid; i < 808; i += 256) {
        int tt = i - 3;
        bool ok = (tt >= 0) && (tt < NFRAMES);
        float m336 = (ok && f >= 336) ? mb[(size_t)(f - 336) * MAGT + tt] : 0.f;
        float m337 = (ok && f >= 337) ? mb[(size_t)(f - 337) * MAGT + tt] : 0.f;
        float m154 = (ok && f >= 154) ? mb[(size_t)(f - 154) * MAGT + tt] : 0.f;
        float m155 = (ok && f >= 155) ? mb[(size_t)(f - 155) * MAGT + tt] : 0.f;
        float m0   = ok ? mb[(size_t)f * MAGT + tt] : 0.f;
        rows[0][i] = (1.f - fr4) * m336 + fr4 * m337;
        rows[1][i] = (1.f - fr5) * m154 + fr5 * m155;
        rows[2][i] = m0;
    }
    __syncthreads();

    char* crow = (char*)f0c + ((size_t)(b * FROWS + f + 1)) * 840 * 64;

    // left pad zeros: tg in [0,4)
    if (tid < 16) {
        int tg = tid >> 2, q = tid & 3;
        int swz = (((tg >> 1) & 3) << 4) | (((tg >> 3) & 1) << 6);
        f16x8 z;
        #pragma unroll
        for (int j = 0; j < 8; ++j) z[j] = (f16)0.f;
        *reinterpret_cast<f16x8*>(crow + ((tg * 64 + q * 16) ^ swz)) = z;
    }

    #pragma unroll
    for (int chunk = 0; chunk < 4; ++chunk) {
        int t = chunk * 256 + tid;
        if (t < NFRAMES) {
            float win[3][7];
            #pragma unroll
            for (int r = 0; r < 3; ++r)
                #pragma unroll
                for (int k = 0; k < 7; ++k)
                    win[r][k] = rows[r][t + k];

            float vals[32];
            #pragma unroll
            for (int o = 0; o < 32; ++o) {
                float a = bias[o];
                #pragma unroll
                for (int r = 0; r < 3; ++r) {
                    const float* wr = wn + (o * 7 + 4 + r) * 7;
                    #pragma unroll
                    for (int kw = 0; kw < 7; ++kw)
                        a = fmaf(win[r][kw], wr[kw], a);
                }
                vals[o] = (a > 0.f) ? a : 0.1f * a;
            }

            #pragma unroll
            for (int o = 0; o < 32; ++o)
                out[(((size_t)b * 32 + o) * NBINS + f) * (size_t)NFRAMES + t] = vals[o];

            int tg = t + 4;
            int swz = (((tg >> 1) & 3) << 4) | (((tg >> 3) & 1) << 6);
            #pragma unroll
            for (int q = 0; q < 4; ++q) {
                f16x8 h;
                #pragma unroll
                for (int j = 0; j < 8; ++j) h[j] = (f16)vals[q * 8 + j];
                *reinterpret_cast<f16x8*>(crow + ((tg * 64 + q * 16) ^ swz)) = h;
            }
        } else if (t < 836) {                 // right pad zeros: tg in [805,840)
            int tg = t + 4;
            int swz = (((tg >> 1) & 3) << 4) | (((tg >> 3) & 1) << 6);
            f16x8 z;
            #pragma unroll
            for (int j = 0; j < 8; ++j) z[j] = (f16)0.f;
            #pragma unroll
            for (int q = 0; q < 4; ++q)
                *reinterpret_cast<f16x8*>(crow + ((tg * 64 + q * 16) ^ swz)) = z;
        }
    }
}

// ------------------------------------------------ one-shot MFMA conv v6 ----
// One tile per block, full-grid TLP; stage via global_load_lds (zero staging
// VGPRs); m204 bijective XCD swizzle with tb-fastest work order.
template<int KW, int STRIDE, int PW, int PAD_IN, int PAD_OUT, int NTB, int MINW, bool DO_LRELU>
__global__ __launch_bounds__(256, MINW) void conv_v6(
    const f16* __restrict__ inC, const f16* __restrict__ Ap,
    const float* __restrict__ bias, float* __restrict__ out,
    f16* __restrict__ outC, int Tout, int TpadIn, int TpadOut)
{
    constexpr int NT    = 64;
    constexpr int TR    = NT * STRIDE + KW - 1;
    constexpr int TRP   = (TR + 1) & ~1;
    constexpr int ROWB  = TRP * 64;
    constexpr int SLR   = TRP * 4;             // 16B slots per f-row
    constexpr int SL    = 6 * SLR;             // active slots
    constexpr int KPT   = (SL + 255) / 256;    // issue groups (unconditional)
    constexpr int TOFF  = (PAD_IN - PW) & 15;
    constexpr int NFOFF = 32 * STRIDE * 64;

    __shared__ char ldsb[KPT * 256 * 16];      // padded: slack absorbs tail group

    const int tid  = threadIdx.x;
    const int lane = tid & 63;
    const int wave = tid >> 6;

    // bijective XCD swizzle (m204), work order: tb fastest, then fblk, then b
    const int NWG = NTB * 129 * 4;
    int lin = blockIdx.x;
    int xcd = lin & 7, sl = lin >> 3;
    const int q = NWG / 8, r = NWG % 8;
    int work = (xcd < r ? xcd * (q + 1) : r * (q + 1) + (xcd - r) * q) + sl;
    const int tb   = work % NTB;
    int rem        = work / NTB;
    const int fblk = rem % 129;
    const int b    = rem / 129;
    const int f0   = fblk * 4;
    const int brow = b * FROWS + f0;           // copy row of fr=0 (fi=f0-1)
    const int t0   = tb * NT;
    const int base_t = t0 * STRIDE + (PAD_IN - PW);

    // ---- stage: branch-free global_load_lds, linear LDS dest
    {
        const char* inB = (const char*)inC;
        #pragma unroll
        for (int k = 0; k < KPT; ++k) {
            int s  = tid + k * 256;
            int fr = s / SLR;
            int s2 = s - fr * SLR;
            __builtin_amdgcn_global_load_lds(
                (const __attribute__((address_space(1))) void*)
                    (inB + ((size_t)(brow + fr) * TpadIn + base_t) * 64 + (size_t)s2 * 16),
                (__attribute__((address_space(3))) void*)
                    (ldsb + (k * 256 + (tid & 192)) * 16),
                16, 0, 0);
        }
    }

    // swizzled LDS read bases
    const int tln = lane & 31;
    const int hi  = lane >> 5;
    int baddr0[KW];
    #pragma unroll
    for (int kw = 0; kw < KW; ++kw) {
        int trow = tln * STRIDE + kw;
        int x = trow + TOFF;
        int swz = (((x >> 1) & 3) << 4) | (((x >> 3) & 1) << 6);
        baddr0[kw] = (trow * 64 + hi * 16) ^ swz;
    }

    float bs[16];
    #pragma unroll
    for (int rr = 0; rr < 16; ++rr) bs[rr] = bias[4 * hi + 8 * (rr >> 2) + (rr & 3)];

    __syncthreads();   // drains vmcnt(0): staged tile ready

    f32x16 acc[2];
    #pragma unroll
    for (int nf = 0; nf < 2; ++nf)
        #pragma unroll
        for (int rr = 0; rr < 16; ++rr) acc[nf][rr] = 0.f;

    const char* lrow = ldsb + wave * ROWB;
    #pragma unroll
    for (int df = 0; df < 3; ++df) {
        f16x8 a[KW * 2];
        #pragma unroll
        for (int kw = 0; kw < KW; ++kw)
            #pragma unroll
            for (int ch = 0; ch < 2; ++ch)
                a[kw * 2 + ch] = *reinterpret_cast<const f16x8*>(
                    Ap + (((df * KW + kw) * 2 + ch) << 9) + lane * 8);
        #pragma unroll
        for (int kw = 0; kw < KW; ++kw)
            #pragma unroll
            for (int ch = 0; ch < 2; ++ch)
                #pragma unroll
                for (int nf = 0; nf < 2; ++nf) {
                    f16x8 bf = *reinterpret_cast<const f16x8*>(
                        lrow + ((baddr0[kw] ^ (ch << 5)) + df * ROWB + nf * NFOFF));
                    acc[nf] = __builtin_amdgcn_mfma_f32_32x32x16_f16(a[kw * 2 + ch], bf, acc[nf], 0, 0, 0);
                }
    }

    // ---------------- epilogue ----------------
    const int f = f0 + wave;
    if (f >= NBINS) return;

    char* crow = nullptr;
    if constexpr (PAD_OUT > 0)
        crow = (char*)outC + ((size_t)(b * FROWS + f + 1)) * TpadOut * 64;

    #pragma unroll
    for (int nf = 0; nf < 2; ++nf) {
        int t = t0 + nf * 32 + tln;
        bool vt = (t < Tout);
        float vals[16];
        #pragma unroll
        for (int rr = 0; rr < 16; ++rr) {
            float v = acc[nf][rr] + bs[rr];
            if (DO_LRELU) v = (v > 0.f) ? v : 0.1f * v;
            vals[rr] = v;
        }
        if (vt) {
            #pragma unroll
            for (int rr = 0; rr < 16; ++rr) {
                int o = 4 * hi + 8 * (rr >> 2) + (rr & 3);
                out[(((size_t)b * 32 + o) * NBINS + f) * Tout + t] = vals[rr];
            }
        }
        if constexpr (PAD_OUT > 0) {
            int tg = t + PAD_OUT;
            int swz = (((tg >> 1) & 3) << 4) | (((tg >> 3) & 1) << 6);
            int rowbyte = (tg * 64) ^ swz;
            #pragma unroll
            for (int qq = 0; qq < 4; ++qq) {
                f16x4 hv;
                #pragma unroll
                for (int rr = 0; rr < 4; ++rr)
                    hv[rr] = vt ? (f16)vals[4 * qq + rr] : (f16)0.f;
                *reinterpret_cast<f16x4*>(crow + (rowbyte ^ ((4 * hi + 8 * qq) << 1))) = hv;
            }
        }
    }
    if constexpr (PAD_OUT > 0) {
        if (tb == 0 && lane < PAD_OUT * 4) {   // left pad zeros
            int tgp = lane >> 2, oct = lane & 3;
            f16x8 z;
            #pragma unroll
            for (int j = 0; j < 8; ++j) z[j] = (f16)0.f;
            *reinterpret_cast<f16x8*>(crow + tgp * 64 + oct * 16) = z;
        }
    }
}

// ------------------------------------------------------- final conv v2 ----
__global__ __launch_bounds__(256) void convo_v2(const f16* __restrict__ inC,
                                                const float* __restrict__ won,
                                                const float* __restrict__ bias,
                                                float* __restrict__ f5,
                                                float* __restrict__ flat)
{
    const int TP4 = 136;
    int blk = blockIdx.x;                  // (b, fpair)
    int b = blk / 257, fp = blk - (b * 257);
    int tid = threadIdx.x;
    int f = fp * 2 + (tid >> 7);
    int t = tid & 127;
    if (f >= NBINS || t >= 101) return;

    float acc = bias[0];
    #pragma unroll
    for (int df = 0; df < 3; ++df) {
        const char* row = (const char*)inC + ((size_t)(b * FROWS + f + df)) * TP4 * 64;
        #pragma unroll
        for (int kw = 0; kw < 3; ++kw) {
            int tg = t + kw;               // (t + kw - 1) + PAD_OUT(1)
            int swz = (((tg >> 1) & 3) << 4) | (((tg >> 3) & 1) << 6);
            #pragma unroll
            for (int q2 = 0; q2 < 4; ++q2) {
                f16x8 h = *reinterpret_cast<const f16x8*>(row + ((tg * 64 + q2 * 16) ^ swz));
                #pragma unroll
                for (int j = 0; j < 8; ++j)
                    acc = fmaf((float)h[j], won[((q2 * 8 + j) * 3 + df) * 3 + kw], acc);
            }
        }
    }
    size_t idx = ((size_t)(b * NBINS + f)) * 101 + t;
    f5[idx] = acc;
    flat[idx] = acc;
}

// ------------------------------------------------------------------ launch --
extern "C" void kernel_launch(void* const* d_in, const int* in_sizes, int n_in,
                              void* d_out, int out_size, void* d_ws, size_t ws_size,
                              hipStream_t stream)
{
    const float* y  = (const float*)d_in[0];
    const float* v0 = (const float*)d_in[1];
    const float* g0 = (const float*)d_in[2];
    const float* b0 = (const float*)d_in[3];
    const float* v1 = (const float*)d_in[4];
    const float* g1 = (const float*)d_in[5];
    const float* b1 = (const float*)d_in[6];
    const float* v2 = (const float*)d_in[7];
    const float* g2 = (const float*)d_in[8];
    const float* b2 = (const float*)d_in[9];
    const float* v3 = (const float*)d_in[10];
    const float* g3 = (const float*)d_in[11];
    const float* b3 = (const float*)d_in[12];
    const float* v4 = (const float*)d_in[13];
    const float* g4 = (const float*)d_in[14];
    const float* b4 = (const float*)d_in[15];
    const float* vo = (const float*)d_in[16];
    const float* go = (const float*)d_in[17];
    const float* bo = (const float*)d_in[18];

    float* out = (float*)d_out;
    float* ws  = (float*)d_ws;

    const size_t SFLAT = (size_t)4 * NBINS * 101;
    const size_t NF0   = (size_t)4 * 32 * NBINS * 801;
    const size_t NF1   = (size_t)4 * 32 * NBINS * 401;
    const size_t NF2   = (size_t)4 * 32 * NBINS * 201;
    const size_t NF3   = (size_t)4 * 32 * NBINS * 101;
    float* oflat = out;
    float* f0 = out + SFLAT;
    float* f1 = f0 + NF0;
    float* f2 = f1 + NF1;
    float* f3 = f2 + NF2;
    float* f4 = f3 + NF3;
    float* f5 = f4 + NF3;

    // mag (stride MAGT) stashed in the (not yet written) fmap1 region
    float* mag = f1;

    // ws layout: fp32 small weights, fp16 A-packs, fp16 activation copies
    const int TP0 = 840, TP1 = 456, TP2 = 264, TP3 = 136, TP4 = 136;
    size_t off = 0;
    float* w0n = ws + off; off += 1568;
    float* won = ws + off; off += 288;
    f16* A1 = (f16*)(ws + off);
    f16* A2 = A1 + 27648;
    f16* A3 = A2 + 27648;
    f16* A4 = A3 + 27648;               // 9216 elements
    f16* f0c = A4 + 9216;               // [4][515][840][32]
    f16* f1c = f0c + (size_t)4 * FROWS * TP0 * 32;   // [4][515][456][32]
    f16* f2c = f1c + (size_t)4 * FROWS * TP1 * 32;   // [4][515][264][32]
    f16* f3c = f2c + (size_t)4 * FROWS * TP2 * 32;   // [4][515][136][32]
    f16* f4c = f3c + (size_t)4 * FROWS * TP3 * 32;   // [4][515][136][32]

    prep_kernel<<<417, 256, 0, stream>>>(v0, g0, v1, g1, v2, g2, v3, g3,
                                         v4, g4, vo, go, w0n, won,
                                         A1, A2, A3, A4,
                                         f0c, f1c, f2c, f3c, f4c);

    stft_v2<<<dim3(101, 4), 256, 0, stream>>>(y, mag);

    double sh4 = -(1000.0 * log(0.001 * (5.0 / 7.0)) - 1000.0 * log(0.001)); // 336.472...
    double sh5 = -(1000.0 * log(0.001 * (6.0 / 7.0)) - 1000.0 * log(0.001)); // 154.150...
    float fr4 = (float)(sh4 - floor(sh4));
    float fr5 = (float)(sh5 - floor(sh5));

    harmonic_kernel<<<dim3(NBINS, 4), 256, 0, stream>>>(mag, w0n, b0, f0, f0c, fr4, fr5);

    // conv chain: one-shot gload_lds-staged, fp16-copy in, fp32 fmap out (+ copy)
    conv_v6<9, 2, 4, 4, 4, 7, 3, true><<<7 * 129 * 4, 256, 0, stream>>>(f0c, A1, b1, f1, f1c, 401, TP0, TP1);
    conv_v6<9, 2, 4, 4, 4, 4, 3, true><<<4 * 129 * 4, 256, 0, stream>>>(f1c, A2, b2, f2, f2c, 201, TP1, TP2);
    conv_v6<9, 2, 4, 4, 5, 2, 3, true><<<2 * 129 * 4, 256, 0, stream>>>(f2c, A3, b3, f3, f3c, 101, TP2, TP3);
    conv_v6<3, 1, 1, 5, 1, 2, 4, true><<<2 * 129 * 4, 256, 0, stream>>>(f3c, A4, b4, f4, f4c, 101, TP3, TP4);

    convo_v2<<<257 * 4, 256, 0, stream>>>(f4c, won, bo, f5, oflat);
}